// Round 10
// baseline (83.083 us; speedup 1.0000x reference)
//
#include <hip/hip_runtime.h>
#include <stdint.h>

// GAT layer: N=4096 nodes, IN=256, H=4 heads, F=64 out/head.
constexpr int NODES = 4096;
constexpr int KIN   = 256;
constexpr int NHEAD = 4;
constexpr int NF    = 64;
constexpr int HFQ   = 256;   // NHEAD*NF
#define L2E 1.44269504088896340736f

typedef __attribute__((ext_vector_type(8))) short short8;
typedef __attribute__((ext_vector_type(4))) float floatx4;

static __device__ __forceinline__ unsigned short f2bf(float f) {
  return __builtin_bit_cast(unsigned short, (__bf16)f);
}

// ---- kernel 1: pack (adj->bitmask via ballot) + proj (h,W->gT3,tables) -----
// blocks 0..1023: pack. block = (i-tile of 16) x (j-quarter of 1024).
//   Lane l reads adj[row][jbase+l] (256 B coalesced); __ballot(a!=0) yields
//   64 adjacency bits = 2 consecutive bm words for the row (transpose via
//   exec mask). LDS-staged, then 64 B-coalesced stores to bm[jw][i].
// blocks 1024..2047: projection with inline fp32->bf16 cvt (as round 9).
__global__ __launch_bounds__(256) void prep_kernel(
    const int* __restrict__ adj, unsigned* __restrict__ bm,
    const float* __restrict__ hin, const float* __restrict__ Win,
    const float* __restrict__ bias, const float* __restrict__ attn_w,
    const float* __restrict__ attn_b,
    unsigned short* __restrict__ gT3, float2* __restrict__ srcP,
    unsigned* __restrict__ eP) {
  __shared__ float2 sred[4][16];
  __shared__ unsigned pk[32][16];
  int tid = threadIdx.x;
  if (blockIdx.x < 1024) {
    int it = blockIdx.x >> 2, jq = blockIdx.x & 3;
    int i0 = it * 16;
    int wave = tid >> 6, lane = tid & 63;
#pragma unroll
    for (int rr = 0; rr < 4; ++rr) {
      int rloc = wave * 4 + rr;
      const int* arow = adj + (size_t)(i0 + rloc) * NODES + jq * 1024 + lane;
#pragma unroll
      for (int c = 0; c < 16; ++c) {
        int a = arow[c * 64];                       // 256 B coalesced
        unsigned long long bal = __ballot(a != 0);  // bit l = row's j=jbase+l
        if (lane == 0) {
          pk[c * 2][rloc]     = (unsigned)bal;
          pk[c * 2 + 1][rloc] = (unsigned)(bal >> 32);
        }
      }
    }
    __syncthreads();
#pragma unroll
    for (int pass = 0; pass < 2; ++pass) {
      int idx = pass * 256 + tid;
      int jwl = idx >> 4, il = idx & 15;
      bm[(size_t)(jq * 32 + jwl) * NODES + i0 + il] = pk[jwl][il];
    }
    return;
  }
  // ---- proj half ----
  int bid = blockIdx.x - 1024;
  int nt = tid >> 6, lane = tid & 63;
  int mt = bid >> 2, h = bid & 3;
  int m0 = mt * 16;
  int r = lane & 15, kg = lane >> 4;
  int col = h * NF + nt * 16 + r;
  floatx4 acc = {0.f, 0.f, 0.f, 0.f};
  const float* Af = hin + (m0 + r) * KIN + kg * 8;
  const float* Bf = Win + col * KIN + kg * 8;
#pragma unroll
  for (int kb = 0; kb < 8; ++kb) {
    float4 fa0 = *reinterpret_cast<const float4*>(Af + kb * 32);
    float4 fa1 = *reinterpret_cast<const float4*>(Af + kb * 32 + 4);
    float4 fb0 = *reinterpret_cast<const float4*>(Bf + kb * 32);
    float4 fb1 = *reinterpret_cast<const float4*>(Bf + kb * 32 + 4);
    short8 a, b;
    a[0] = (short)f2bf(fa0.x); a[1] = (short)f2bf(fa0.y);
    a[2] = (short)f2bf(fa0.z); a[3] = (short)f2bf(fa0.w);
    a[4] = (short)f2bf(fa1.x); a[5] = (short)f2bf(fa1.y);
    a[6] = (short)f2bf(fa1.z); a[7] = (short)f2bf(fa1.w);
    b[0] = (short)f2bf(fb0.x); b[1] = (short)f2bf(fb0.y);
    b[2] = (short)f2bf(fb0.z); b[3] = (short)f2bf(fb0.w);
    b[4] = (short)f2bf(fb1.x); b[5] = (short)f2bf(fb1.y);
    b[6] = (short)f2bf(fb1.z); b[7] = (short)f2bf(fb1.w);
    acc = __builtin_amdgcn_mfma_f32_16x16x32_bf16(a, b, acc, 0, 0, 0);
  }
  float bv = bias[col];
  float was = attn_w[nt * 16 + r], wad = attn_w[64 + nt * 16 + r];
  float ps[4], pd[4];
#pragma unroll
  for (int q = 0; q < 4; ++q) {
    int row = m0 + kg * 4 + q;            // C/D: row=(lane>>4)*4+q, col=lane&15
    float v = acc[q] + bv;
    int si = (row >> 5) * 8192 + h * 2048 + nt * 512 +
             (((row >> 3) & 3) * 16 + r) * 8 + (row & 7);
    gT3[si] = f2bf(v);
    ps[q] = v * was;
    pd[q] = v * wad;
  }
#pragma unroll
  for (int m = 8; m >= 1; m >>= 1)
#pragma unroll
    for (int q = 0; q < 4; ++q) {
      ps[q] += __shfl_xor(ps[q], m, 64);
      pd[q] += __shfl_xor(pd[q], m, 64);
    }
  if ((lane & 15) == 0)
#pragma unroll
    for (int q = 0; q < 4; ++q)
      sred[nt][kg * 4 + q] = float2{ps[q], pd[q]};
  __syncthreads();
  if (tid < 16) {
    int row = tid;
    float s = sred[0][row].x + sred[1][row].x + sred[2][row].x + sred[3][row].x + attn_b[0];
    float d = sred[0][row].y + sred[1][row].y + sred[2][row].y + sred[3][row].y;
    float2 sp;
    sp.x = exp2f(s * L2E);
    sp.y = exp2f(0.2f * s * L2E);
    srcP[(m0 + row) * NHEAD + h] = sp;
    float e1 = exp2f(d * L2E), e2 = exp2f(0.2f * d * L2E);
    eP[h * NODES + m0 + row] = ((unsigned)f2bf(e2) << 16) | (unsigned)f2bf(e1);
  }
}

// ---- kernel 2: fused attention, 16x16x32 MFMA, 8 waves/SIMD ----------------
// grid (NP, 256): blockIdx.x = j-partition (linear%8 -> one per XCD),
// blockIdx.y = i-tile of 16 rows. block 256 = 4 waves (1 head each).
// w = max(es1*e1, es2*e2)  (== exp(lrelu(s+d)), exact identity), masked by bm.
// bm/ep software-pipelined one step ahead; ones-MFMA computes denominator.
__global__ __launch_bounds__(256, 8) void attn_kernel(
    const unsigned* __restrict__ bm, const unsigned short* __restrict__ gT3,
    const float2* __restrict__ srcP, const unsigned* __restrict__ eP,
    float* __restrict__ pnum, float* __restrict__ pden, int JP) {
  int tid = threadIdx.x;
  int hh = tid >> 6, lane = tid & 63;
  int il = lane & 15, kg = lane >> 4;
  int part = blockIdx.x, itile = blockIdx.y;
  int jstart = part * JP;
  int i = itile * 16 + il;                // attention row this lane owns

  float2 sp = srcP[i * NHEAD + hh];
  float es1 = sp.x, es2 = sp.y;

  floatx4 acc0 = {0.f, 0.f, 0.f, 0.f};
  floatx4 acc1 = acc0, acc2 = acc0, acc3 = acc0, accd = acc0;

  short8 ones;
#pragma unroll
  for (int r = 0; r < 8; ++r) ones[r] = (short)0x3F80;  // bf16 1.0

  int jt0 = jstart >> 5;
  const unsigned* bmp = bm + (size_t)jt0 * NODES + i;
  const unsigned* epp = eP + hh * NODES + jstart + kg * 8;
  const unsigned short* Atp = gT3 + (size_t)jt0 * 8192 + hh * 2048 + lane * 8;

  unsigned mwd = *bmp;
  uint4 ea = *reinterpret_cast<const uint4*>(epp);
  uint4 eb = *reinterpret_cast<const uint4*>(epp + 4);

  int nsteps = JP / 32;

#define STEP_BODY {                                                         \
    unsigned mb = (mwd >> (kg * 8)) & 0xFFu;                                \
    unsigned ev[8] = {ea.x, ea.y, ea.z, ea.w, eb.x, eb.y, eb.z, eb.w};      \
    short8 bfr;                                                             \
    _Pragma("unroll")                                                       \
    for (int r = 0; r < 8; ++r) {                                           \
      float e1f = __builtin_bit_cast(float, ev[r] << 16);                   \
      float e2f = __builtin_bit_cast(float, ev[r] & 0xFFFF0000u);           \
      float w = fmaxf(es1 * e1f, es2 * e2f);                                \
      w = (mb & (1u << r)) ? w : 0.f;                                       \
      bfr[r] = (short)f2bf(w);                                              \
    }                                                                       \
    const short8 a0 = *reinterpret_cast<const short8*>(Atp);                \
    const short8 a1 = *reinterpret_cast<const short8*>(Atp + 512);          \
    const short8 a2 = *reinterpret_cast<const short8*>(Atp + 1024);         \
    const short8 a3 = *reinterpret_cast<const short8*>(Atp + 1536);         \
    acc0 = __builtin_amdgcn_mfma_f32_16x16x32_bf16(a0, bfr, acc0, 0, 0, 0); \
    acc1 = __builtin_amdgcn_mfma_f32_16x16x32_bf16(a1, bfr, acc1, 0, 0, 0); \
    acc2 = __builtin_amdgcn_mfma_f32_16x16x32_bf16(a2, bfr, acc2, 0, 0, 0); \
    acc3 = __builtin_amdgcn_mfma_f32_16x16x32_bf16(a3, bfr, acc3, 0, 0, 0); \
    accd = __builtin_amdgcn_mfma_f32_16x16x32_bf16(ones, bfr, accd, 0, 0, 0);\
  }

  for (int stp = 0; stp < nsteps - 1; ++stp) {
    unsigned mwd_n = bmp[NODES];                                  // prefetch
    uint4 ea_n = *reinterpret_cast<const uint4*>(epp + 32);
    uint4 eb_n = *reinterpret_cast<const uint4*>(epp + 36);
    STEP_BODY;
    mwd = mwd_n; ea = ea_n; eb = eb_n;
    bmp += NODES; epp += 32; Atp += 8192;
  }
  STEP_BODY;                                                      // last step
#undef STEP_BODY

  // denominator: all c-rows of accd identical; col = il
  if (kg == 0)
    pden[(size_t)part * (NODES * NHEAD) + i * NHEAD + hh] = accd[0];

  // numerator: C/D layout col=lane&15 (=i), row c_in_tile = kg*4 + q
  float* pbase = pnum + (size_t)part * (NODES * HFQ) + (size_t)i * HFQ + hh * NF;
#pragma unroll
  for (int q = 0; q < 4; ++q) {
    int c = kg * 4 + q;
    pbase[c] = acc0[q];
    pbase[16 + c] = acc1[q];
    pbase[32 + c] = acc2[q];
    pbase[48 + c] = acc3[q];
  }
}

// ---- kernel 3: combine partials, normalize, mean over heads ----------------
__global__ __launch_bounds__(256) void combine_kernel(
    const float* __restrict__ pnum, const float* __restrict__ pden,
    float* __restrict__ out, int NP) {
  int idx = blockIdx.x * 256 + threadIdx.x;
  int i = idx >> 6, f = idx & 63;
  float o = 0.f;
#pragma unroll
  for (int hh = 0; hh < NHEAD; ++hh) {
    float num = 0.f, den = 0.f;
    for (int p = 0; p < NP; ++p) {
      num += pnum[p * (NODES * HFQ) + i * HFQ + hh * NF + f];
      den += pden[p * (NODES * NHEAD) + i * NHEAD + hh];
    }
    o += num / den;
  }
  out[idx] = 0.25f * o;
}

extern "C" void kernel_launch(void* const* d_in, const int* in_sizes, int n_in,
                              void* d_out, int out_size, void* d_ws, size_t ws_size,
                              hipStream_t stream) {
  const float* hin = (const float*)d_in[0];
  const int* adj   = (const int*)d_in[1];
  const float* W   = (const float*)d_in[2];
  const float* b   = (const float*)d_in[3];
  const float* aw  = (const float*)d_in[4];
  const float* ab  = (const float*)d_in[5];
  float* out = (float*)d_out;
  char* ws = (char*)d_ws;

  unsigned short* gT3 = (unsigned short*)(ws + 0x000000);  // 2 MB (frag-ordered)
  float2* srcP        = (float2*)(ws + 0x200000);          // 128 KB
  unsigned* eP        = (unsigned*)(ws + 0x220000);        // 64 KB
  unsigned* bm        = (unsigned*)(ws + 0x240000);        // 2 MB bitmask
  float* pden         = (float*)(ws + 0x440000);           // up to 512 KB
  float* pnum         = (float*)(ws + 0x500000);           // NP * 4 MB
  const size_t base = 0x500000;

  int NP = 2;
  if (ws_size >= base + 8ull * NODES * HFQ * 4) NP = 8;
  else if (ws_size >= base + 4ull * NODES * HFQ * 4) NP = 4;
  int JP = NODES / NP;

  prep_kernel<<<2048, 256, 0, stream>>>(adj, bm, hin, W, b, aw, ab, gT3, srcP, eP);
  attn_kernel<<<dim3(NP, 256), 256, 0, stream>>>(bm, gT3, srcP, eP, pnum, pden, JP);
  combine_kernel<<<1024, 256, 0, stream>>>(pnum, pden, out, NP);
}

// Round 11
// 70.825 us; speedup vs baseline: 1.1731x; 1.1731x over previous
//
#include <hip/hip_runtime.h>
#include <stdint.h>

// GAT layer: N=4096 nodes, IN=256, H=4 heads, F=64 out/head.
constexpr int NODES = 4096;
constexpr int KIN   = 256;
constexpr int NHEAD = 4;
constexpr int NF    = 64;
constexpr int HFQ   = 256;   // NHEAD*NF
#define L2E 1.44269504088896340736f

typedef __attribute__((ext_vector_type(8))) short short8;
typedef __attribute__((ext_vector_type(4))) float floatx4;

static __device__ __forceinline__ unsigned short f2bf(float f) {
  return __builtin_bit_cast(unsigned short, (__bf16)f);
}

// ---- kernel 1: pack (adj->bitmask, shfl-transpose) + proj ------------------
// blocks 0..1023: pack. block = (i-tile of 16) x (j-quarter of 1024).
//   Lane l loads int4 (16 B) -> 1 KB coalesced per wave-load, 16 independent
//   loads per wave (deep ILP). Per load: nibble of 4 cmp bits, shifted to its
//   absolute slot, OR-reduced across the 8-lane group via 3 shfl_xor -> full
//   32-bit bm word in registers (no vcc serialization). LDS-staged, coalesced
//   write to bm[jw][i] (identical layout to prior rounds; attn untouched).
// blocks 1024..2047: projection with inline fp32->bf16 cvt (unchanged).
__global__ __launch_bounds__(256) void prep_kernel(
    const int* __restrict__ adj, unsigned* __restrict__ bm,
    const float* __restrict__ hin, const float* __restrict__ Win,
    const float* __restrict__ bias, const float* __restrict__ attn_w,
    const float* __restrict__ attn_b,
    unsigned short* __restrict__ gT3, float2* __restrict__ srcP,
    unsigned* __restrict__ eP) {
  __shared__ float2 sred[4][16];
  __shared__ unsigned pk[32][17];
  int tid = threadIdx.x;
  if (blockIdx.x < 1024) {
    int it = blockIdx.x >> 2, jq = blockIdx.x & 3;
    int i0 = it * 16;
    int wave = tid >> 6, lane = tid & 63;
    int lsh = (lane & 7) * 4;
#pragma unroll
    for (int rr = 0; rr < 4; ++rr) {
      int rloc = wave * 4 + rr;
      const int4* arow = reinterpret_cast<const int4*>(
          adj + (size_t)(i0 + rloc) * NODES + jq * 1024) + lane;
#pragma unroll
      for (int seg = 0; seg < 4; ++seg) {
        int4 a = arow[seg * 64];              // 1 KB coalesced wave-load
        unsigned nib = (a.x != 0 ? 1u : 0u) | (a.y != 0 ? 2u : 0u)
                     | (a.z != 0 ? 4u : 0u) | (a.w != 0 ? 8u : 0u);
        unsigned wp = nib << lsh;
        wp |= (unsigned)__shfl_xor((int)wp, 1, 64);
        wp |= (unsigned)__shfl_xor((int)wp, 2, 64);
        wp |= (unsigned)__shfl_xor((int)wp, 4, 64);
        if ((lane & 7) == 0)
          pk[seg * 8 + (lane >> 3)][rloc] = wp;
      }
    }
    __syncthreads();
#pragma unroll
    for (int pass = 0; pass < 2; ++pass) {
      int idx = pass * 256 + tid;
      int jwl = idx >> 4, il = idx & 15;
      bm[(size_t)(jq * 32 + jwl) * NODES + i0 + il] = pk[jwl][il];
    }
    return;
  }
  // ---- proj half ----
  int bid = blockIdx.x - 1024;
  int nt = tid >> 6, lane = tid & 63;
  int mt = bid >> 2, h = bid & 3;
  int m0 = mt * 16;
  int r = lane & 15, kg = lane >> 4;
  int col = h * NF + nt * 16 + r;
  floatx4 acc = {0.f, 0.f, 0.f, 0.f};
  const float* Af = hin + (m0 + r) * KIN + kg * 8;
  const float* Bf = Win + col * KIN + kg * 8;
#pragma unroll
  for (int kb = 0; kb < 8; ++kb) {
    float4 fa0 = *reinterpret_cast<const float4*>(Af + kb * 32);
    float4 fa1 = *reinterpret_cast<const float4*>(Af + kb * 32 + 4);
    float4 fb0 = *reinterpret_cast<const float4*>(Bf + kb * 32);
    float4 fb1 = *reinterpret_cast<const float4*>(Bf + kb * 32 + 4);
    short8 a, b;
    a[0] = (short)f2bf(fa0.x); a[1] = (short)f2bf(fa0.y);
    a[2] = (short)f2bf(fa0.z); a[3] = (short)f2bf(fa0.w);
    a[4] = (short)f2bf(fa1.x); a[5] = (short)f2bf(fa1.y);
    a[6] = (short)f2bf(fa1.z); a[7] = (short)f2bf(fa1.w);
    b[0] = (short)f2bf(fb0.x); b[1] = (short)f2bf(fb0.y);
    b[2] = (short)f2bf(fb0.z); b[3] = (short)f2bf(fb0.w);
    b[4] = (short)f2bf(fb1.x); b[5] = (short)f2bf(fb1.y);
    b[6] = (short)f2bf(fb1.z); b[7] = (short)f2bf(fb1.w);
    acc = __builtin_amdgcn_mfma_f32_16x16x32_bf16(a, b, acc, 0, 0, 0);
  }
  float bv = bias[col];
  float was = attn_w[nt * 16 + r], wad = attn_w[64 + nt * 16 + r];
  float ps[4], pd[4];
#pragma unroll
  for (int q = 0; q < 4; ++q) {
    int row = m0 + kg * 4 + q;            // C/D: row=(lane>>4)*4+q, col=lane&15
    float v = acc[q] + bv;
    int si = (row >> 5) * 8192 + h * 2048 + nt * 512 +
             (((row >> 3) & 3) * 16 + r) * 8 + (row & 7);
    gT3[si] = f2bf(v);
    ps[q] = v * was;
    pd[q] = v * wad;
  }
#pragma unroll
  for (int m = 8; m >= 1; m >>= 1)
#pragma unroll
    for (int q = 0; q < 4; ++q) {
      ps[q] += __shfl_xor(ps[q], m, 64);
      pd[q] += __shfl_xor(pd[q], m, 64);
    }
  if ((lane & 15) == 0)
#pragma unroll
    for (int q = 0; q < 4; ++q)
      sred[nt][kg * 4 + q] = float2{ps[q], pd[q]};
  __syncthreads();
  if (tid < 16) {
    int row = tid;
    float s = sred[0][row].x + sred[1][row].x + sred[2][row].x + sred[3][row].x + attn_b[0];
    float d = sred[0][row].y + sred[1][row].y + sred[2][row].y + sred[3][row].y;
    float2 sp;
    sp.x = exp2f(s * L2E);
    sp.y = exp2f(0.2f * s * L2E);
    srcP[(m0 + row) * NHEAD + h] = sp;
    float e1 = exp2f(d * L2E), e2 = exp2f(0.2f * d * L2E);
    eP[h * NODES + m0 + row] = ((unsigned)f2bf(e2) << 16) | (unsigned)f2bf(e1);
  }
}

// ---- kernel 2: fused attention, 16x16x32 MFMA, 8 waves/SIMD ----------------
// grid (NP, 256): blockIdx.x = j-partition (linear%8 -> one per XCD),
// blockIdx.y = i-tile of 16 rows. block 256 = 4 waves (1 head each).
// w = max(es1*e1, es2*e2)  (== exp(lrelu(s+d)), exact identity), masked by bm.
// bm/ep software-pipelined one step ahead; ones-MFMA computes denominator.
__global__ __launch_bounds__(256, 8) void attn_kernel(
    const unsigned* __restrict__ bm, const unsigned short* __restrict__ gT3,
    const float2* __restrict__ srcP, const unsigned* __restrict__ eP,
    float* __restrict__ pnum, float* __restrict__ pden, int JP) {
  int tid = threadIdx.x;
  int hh = tid >> 6, lane = tid & 63;
  int il = lane & 15, kg = lane >> 4;
  int part = blockIdx.x, itile = blockIdx.y;
  int jstart = part * JP;
  int i = itile * 16 + il;                // attention row this lane owns

  float2 sp = srcP[i * NHEAD + hh];
  float es1 = sp.x, es2 = sp.y;

  floatx4 acc0 = {0.f, 0.f, 0.f, 0.f};
  floatx4 acc1 = acc0, acc2 = acc0, acc3 = acc0, accd = acc0;

  short8 ones;
#pragma unroll
  for (int r = 0; r < 8; ++r) ones[r] = (short)0x3F80;  // bf16 1.0

  int jt0 = jstart >> 5;
  const unsigned* bmp = bm + (size_t)jt0 * NODES + i;
  const unsigned* epp = eP + hh * NODES + jstart + kg * 8;
  const unsigned short* Atp = gT3 + (size_t)jt0 * 8192 + hh * 2048 + lane * 8;

  unsigned mwd = *bmp;
  uint4 ea = *reinterpret_cast<const uint4*>(epp);
  uint4 eb = *reinterpret_cast<const uint4*>(epp + 4);

  int nsteps = JP / 32;

#define STEP_BODY {                                                         \
    unsigned mb = (mwd >> (kg * 8)) & 0xFFu;                                \
    unsigned ev[8] = {ea.x, ea.y, ea.z, ea.w, eb.x, eb.y, eb.z, eb.w};      \
    short8 bfr;                                                             \
    _Pragma("unroll")                                                       \
    for (int r = 0; r < 8; ++r) {                                           \
      float e1f = __builtin_bit_cast(float, ev[r] << 16);                   \
      float e2f = __builtin_bit_cast(float, ev[r] & 0xFFFF0000u);           \
      float w = fmaxf(es1 * e1f, es2 * e2f);                                \
      w = (mb & (1u << r)) ? w : 0.f;                                       \
      bfr[r] = (short)f2bf(w);                                              \
    }                                                                       \
    const short8 a0 = *reinterpret_cast<const short8*>(Atp);                \
    const short8 a1 = *reinterpret_cast<const short8*>(Atp + 512);          \
    const short8 a2 = *reinterpret_cast<const short8*>(Atp + 1024);         \
    const short8 a3 = *reinterpret_cast<const short8*>(Atp + 1536);         \
    acc0 = __builtin_amdgcn_mfma_f32_16x16x32_bf16(a0, bfr, acc0, 0, 0, 0); \
    acc1 = __builtin_amdgcn_mfma_f32_16x16x32_bf16(a1, bfr, acc1, 0, 0, 0); \
    acc2 = __builtin_amdgcn_mfma_f32_16x16x32_bf16(a2, bfr, acc2, 0, 0, 0); \
    acc3 = __builtin_amdgcn_mfma_f32_16x16x32_bf16(a3, bfr, acc3, 0, 0, 0); \
    accd = __builtin_amdgcn_mfma_f32_16x16x32_bf16(ones, bfr, accd, 0, 0, 0);\
  }

  for (int stp = 0; stp < nsteps - 1; ++stp) {
    unsigned mwd_n = bmp[NODES];                                  // prefetch
    uint4 ea_n = *reinterpret_cast<const uint4*>(epp + 32);
    uint4 eb_n = *reinterpret_cast<const uint4*>(epp + 36);
    STEP_BODY;
    mwd = mwd_n; ea = ea_n; eb = eb_n;
    bmp += NODES; epp += 32; Atp += 8192;
  }
  STEP_BODY;                                                      // last step
#undef STEP_BODY

  // denominator: all c-rows of accd identical; col = il
  if (kg == 0)
    pden[(size_t)part * (NODES * NHEAD) + i * NHEAD + hh] = accd[0];

  // numerator: C/D layout col=lane&15 (=i), row c_in_tile = kg*4 + q
  float* pbase = pnum + (size_t)part * (NODES * HFQ) + (size_t)i * HFQ + hh * NF;
#pragma unroll
  for (int q = 0; q < 4; ++q) {
    int c = kg * 4 + q;
    pbase[c] = acc0[q];
    pbase[16 + c] = acc1[q];
    pbase[32 + c] = acc2[q];
    pbase[48 + c] = acc3[q];
  }
}

// ---- kernel 3: combine partials, normalize, mean over heads ----------------
__global__ __launch_bounds__(256) void combine_kernel(
    const float* __restrict__ pnum, const float* __restrict__ pden,
    float* __restrict__ out, int NP) {
  int idx = blockIdx.x * 256 + threadIdx.x;
  int i = idx >> 6, f = idx & 63;
  float o = 0.f;
#pragma unroll
  for (int hh = 0; hh < NHEAD; ++hh) {
    float num = 0.f, den = 0.f;
    for (int p = 0; p < NP; ++p) {
      num += pnum[p * (NODES * HFQ) + i * HFQ + hh * NF + f];
      den += pden[p * (NODES * NHEAD) + i * NHEAD + hh];
    }
    o += num / den;
  }
  out[idx] = 0.25f * o;
}

extern "C" void kernel_launch(void* const* d_in, const int* in_sizes, int n_in,
                              void* d_out, int out_size, void* d_ws, size_t ws_size,
                              hipStream_t stream) {
  const float* hin = (const float*)d_in[0];
  const int* adj   = (const int*)d_in[1];
  const float* W   = (const float*)d_in[2];
  const float* b   = (const float*)d_in[3];
  const float* aw  = (const float*)d_in[4];
  const float* ab  = (const float*)d_in[5];
  float* out = (float*)d_out;
  char* ws = (char*)d_ws;

  unsigned short* gT3 = (unsigned short*)(ws + 0x000000);  // 2 MB (frag-ordered)
  float2* srcP        = (float2*)(ws + 0x200000);          // 128 KB
  unsigned* eP        = (unsigned*)(ws + 0x220000);        // 64 KB
  unsigned* bm        = (unsigned*)(ws + 0x240000);        // 2 MB bitmask
  float* pden         = (float*)(ws + 0x440000);           // up to 512 KB
  float* pnum         = (float*)(ws + 0x500000);           // NP * 4 MB
  const size_t base = 0x500000;

  int NP = 2;
  if (ws_size >= base + 8ull * NODES * HFQ * 4) NP = 8;
  else if (ws_size >= base + 4ull * NODES * HFQ * 4) NP = 4;
  int JP = NODES / NP;

  prep_kernel<<<2048, 256, 0, stream>>>(adj, bm, hin, W, b, aw, ab, gT3, srcP, eP);
  attn_kernel<<<dim3(NP, 256), 256, 0, stream>>>(bm, gT3, srcP, eP, pnum, pden, JP);
  combine_kernel<<<1024, 256, 0, stream>>>(pnum, pden, out, NP);
}